// Round 14
// baseline (412.992 us; speedup 1.0000x reference)
//
#include <hip/hip_runtime.h>
#include <hip/hip_bf16.h>

#define VOCAB 2048
#define AROW  2304                 // bytes per a8 row (h[2048] || x[256], fp8)
#define TLEN  32
#define BATCH 64
#define NBLK  256
#define NCG   256                  // column groups: 8 vocab cols each
#define ASLOT (BATCH * AROW)

typedef __attribute__((ext_vector_type(4))) float f32x4;

// ---------------- init: a8 slot0 h-region = 0, arrivals = 0 ----------------
__global__ void k_init(unsigned char* __restrict__ a8, unsigned* __restrict__ arrv) {
  int i = blockIdx.x * 256 + threadIdx.x;   // grid 512*256 = 131072
  if (i < 32768) {                           // 64 rows x 2048 B of h zeros
    int row = i >> 9;
    *(unsigned*)(a8 + (size_t)row * AROW + ((i & 511) << 2)) = 0u;
  }
  if (i < 512) arrv[i] = 0;                  // arrvA[256] + arrvB[256]
}

// -------- transpose+convert: src[K][8192] f32 -> B8[n][koff+k] fp8*32 --------
__global__ void k_conv(const float* __restrict__ src,
                       unsigned char* __restrict__ dst, int koff) {
  __shared__ unsigned char tile[64][80];
  int k0 = (blockIdx.x >> 7) * 64;
  int n0 = (blockIdx.x & 127) * 64;
  int tid = threadIdx.x;
  {
    int kl = tid >> 2;
    int nq = (tid & 3) << 4;
    const float* s = src + (size_t)(k0 + kl) * 8192 + n0 + nq;
#pragma unroll
    for (int i = 0; i < 4; ++i) {
      float4 v = *reinterpret_cast<const float4*>(s + i * 4);
      unsigned pa = (unsigned)__builtin_amdgcn_cvt_pk_fp8_f32(v.x * 32.f, v.y * 32.f, 0, false);
      unsigned pb = (unsigned)__builtin_amdgcn_cvt_pk_fp8_f32(v.z * 32.f, v.w * 32.f, 0, false);
      tile[nq + i * 4 + 0][kl] = (unsigned char)(pa & 0xFF);
      tile[nq + i * 4 + 1][kl] = (unsigned char)((pa >> 8) & 0xFF);
      tile[nq + i * 4 + 2][kl] = (unsigned char)(pb & 0xFF);
      tile[nq + i * 4 + 3][kl] = (unsigned char)((pb >> 8) & 0xFF);
    }
  }
  __syncthreads();
  {
    int nl = tid >> 2;
    int kq = (tid & 3) << 4;
    *(uint4*)(dst + (size_t)(n0 + nl) * AROW + koff + k0 + kq) =
        *(const uint4*)&tile[nl][kq];
  }
}

// ---- gather: a8[t][b][2048+c] = fp8(emb[tokens[b][t]][c] * 256) ----
__global__ void k_gather(const int* __restrict__ tokens,
                         const float* __restrict__ emb,
                         unsigned char* __restrict__ a8) {
  int tid = threadIdx.x;
  int row = blockIdx.x * 4 + (tid >> 6);   // 512 blocks -> 2048 rows
  int lane = tid & 63;
  int t = row >> 6, b = row & 63;
  int tok = tokens[b * TLEN + t];
  float4 v = *reinterpret_cast<const float4*>(emb + (size_t)tok * 256 + lane * 4);
  unsigned pa = (unsigned)__builtin_amdgcn_cvt_pk_fp8_f32(v.x * 256.f, v.y * 256.f, 0, false);
  unsigned pb = (unsigned)__builtin_amdgcn_cvt_pk_fp8_f32(v.z * 256.f, v.w * 256.f, 0, false);
  *(unsigned*)(a8 + (size_t)t * ASLOT + (size_t)b * AROW + 2048 + lane * 4) =
      (pa & 0xFFFFu) | (pb << 16);
}

__device__ __forceinline__ void store_agent_u32(unsigned* p, unsigned v) {
  __hip_atomic_store(p, v, __ATOMIC_RELAXED, __HIP_MEMORY_SCOPE_AGENT);
}
__device__ __forceinline__ unsigned long long load_agent_u64(const void* p) {
  return __hip_atomic_load((const unsigned long long*)p, __ATOMIC_RELAXED,
                           __HIP_MEMORY_SCOPE_AGENT);
}
__device__ __forceinline__ void store_agent_f32(float* p, float v) {
  __hip_atomic_store(p, v, __ATOMIC_RELAXED, __HIP_MEMORY_SCOPE_AGENT);
}
__device__ __forceinline__ float2 load_agent_f32x2(const float* p) {
  unsigned long long u = load_agent_u64(p);
  float2 f;
  __builtin_memcpy(&f, &u, 8);
  return f;
}

// Direct-poll chain wait: wave 0 polls all 256 arrival words (monotone),
// no release hop, deadlock-free. Arrivals are ~one half-GEMM old when this
// runs (stagger), so the first poll normally succeeds.
__device__ __forceinline__ void chain_wait(unsigned* arrv, unsigned want,
                                           int tid, int lane) {
  if (tid < 64) {
    for (;;) {
      unsigned long long a = load_agent_u64(arrv + 2 * lane);
      unsigned long long b = load_agent_u64(arrv + 128 + 2 * lane);
      bool ok = ((unsigned)a >= want) && ((unsigned)(a >> 32) >= want) &&
                ((unsigned)b >= want) && ((unsigned)(b >> 32) >= want);
      if (__all(ok)) break;
      __builtin_amdgcn_s_sleep(2);
    }
  }
  __syncthreads();
}

// ---------------- persistent kernel: staggered dual chains ----------------
// 256 blocks x 512 threads. Block j owns 8 vocab cols (cg=j), all 4 gates
// (32 z-cols, 2 n-frags packing 2 gates each). Rows split into chain A
// (0-31) and chain B (32-63) -- independent recurrences with separate
// arrival arrays, interleaved so each chain's sync wait is overlapped by
// the other chain's compute. fp8 GEMM (r13 numerics). B panel = 36 VGPRs,
// resident; A panel fully prefetched (18 loads) per half.
__global__ __launch_bounds__(512, 1) void k_persist(
    const int* __restrict__ tokens,
    const unsigned char* __restrict__ B8,     // [8192][2304] fp8 (W*32)
    unsigned char* __restrict__ a8,           // [33][64][2304] fp8 (h||x)*256
    const float* __restrict__ bias,           // [8192]
    float* __restrict__ stats,                // [2][3][64][256]
    float* __restrict__ out,                  // [64][32][64]
    unsigned* __restrict__ arrvA,             // [256]
    unsigned* __restrict__ arrvB) {           // [256]
  const int tid = threadIdx.x;
  const int lane = tid & 63;
  const int wid = tid >> 6;                  // 0..7 = K-split (288 B each)
  const int j = blockIdx.x;
  const int cg = j;

  __shared__ float racc[8][2][2][4][64];   // [wid][mf][nf][r][lane] 64KB
  __shared__ float spart[TLEN][3];
  __shared__ float sval[TLEN];

  const int rr = lane & 15;
  const int kg = lane >> 4;
  const int s_ = rr >> 3;                   // gate-pair half
  const int v = (cg << 3) + (rr & 7);       // global vocab col

  // ---- B panel resident (36 VGPRs): nf0 = gates i/f, nf1 = gates g/o ----
  long Bf[9][2];
#pragma unroll
  for (int nf = 0; nf < 2; ++nf) {
    const unsigned char* bp = B8 + (size_t)(((nf * 2 + s_) << 11) + v) * AROW +
                              wid * 288 + kg * 8;
#pragma unroll
    for (int it = 0; it < 9; ++it) Bf[it][nf] = *(const long*)(bp + it * 32);
  }

  const float bias0 = bias[s_ * 2048 + v];        // i (s_=0) / f (s_=1)
  const float bias1 = bias[(2 + s_) * 2048 + v];  // g (s_=0) / o (s_=1)
  const int m_e = wid >> 2, r_e = wid & 3;
  float c_reg[2] = {0.f, 0.f};

  for (int t = 0; t <= 30; ++t) {            // t=31 GEMM produces unused h(32)
    const int par = t & 1;
    const unsigned char* a8cur = a8 + (size_t)t * ASLOT;
    unsigned char* a8nxt = a8 + (size_t)(t + 1) * ASLOT;

#pragma unroll
    for (int ch = 0; ch < 2; ++ch) {
      const int r0 = ch << 5;
      unsigned* arrv = ch ? arrvB : arrvA;

      if (t > 0) chain_wait(arrv, (unsigned)t, tid, lane);

      // bounds load for this chain's rows (blocks j in [r0, r0+32))
      float2 sva, svb;
      const bool do_stat = (t > 0) && (j >= r0) && (j < r0 + 32) && (wid < 3);
      if (do_stat) {
        const float* st = stats + par * 3 * BATCH * NCG +
                          (wid * BATCH + j) * NCG + lane * 4;
        sva = load_agent_f32x2(st);
        svb = load_agent_f32x2(st + 2);
      }

      // GEMM: z[32 rows x 32 zcols], K=2304, 8 waves split K, full prefetch
      f32x4 acc[2][2];
#pragma unroll
      for (int mf = 0; mf < 2; ++mf)
#pragma unroll
        for (int nf = 0; nf < 2; ++nf) acc[mf][nf] = (f32x4){0.f, 0.f, 0.f, 0.f};

      long Aw[9][2];
      {
        const unsigned char* ap = a8cur + (size_t)(r0 + rr) * AROW + wid * 288 + kg * 8;
#pragma unroll
        for (int it = 0; it < 9; ++it) {
          Aw[it][0] = *(const long*)(ap + it * 32);
          Aw[it][1] = *(const long*)(ap + 16 * AROW + it * 32);
        }
      }
#pragma unroll
      for (int it = 0; it < 9; ++it)
#pragma unroll
        for (int mf = 0; mf < 2; ++mf)
#pragma unroll
          for (int nf = 0; nf < 2; ++nf)
            acc[mf][nf] = __builtin_amdgcn_mfma_f32_16x16x32_fp8_fp8(
                Aw[it][mf], Bf[it][nf], acc[mf][nf], 0, 0, 0);

      // cross-wave K reduction
#pragma unroll
      for (int mf = 0; mf < 2; ++mf)
#pragma unroll
        for (int nf = 0; nf < 2; ++nf)
#pragma unroll
          for (int r = 0; r < 4; ++r) racc[wid][mf][nf][r][lane] = acc[mf][nf][r];
      __syncthreads();

      if (do_stat) {
        float a = sva.x + sva.y + svb.x + svb.y;
#pragma unroll
        for (int mm = 1; mm <= 32; mm <<= 1) a += __shfl_xor(a, mm);
        if (lane == 0) spart[t][wid] = a;
      }

      // epilogue: one cell per thread (rowg, v)
      const int rowg = r0 + m_e * 16 + kg * 4 + r_e;
      float z0 = 0.f, z1 = 0.f;
#pragma unroll
      for (int w = 0; w < 8; ++w) {
        z0 += racc[w][m_e][0][r_e][lane];
        z1 += racc[w][m_e][1][r_e][lane];
      }
      z0 = z0 * (1.f / 8192.f) + bias0;
      z1 = z1 * (1.f / 8192.f) + bias1;
      float o0 = __shfl_xor(z0, 8);
      float o1 = __shfl_xor(z1, 8);
      float zi = s_ ? o0 : z0;
      float zf = s_ ? z0 : o0;
      float zg = s_ ? o1 : z1;
      float zo = s_ ? z1 : o1;
      float gi = 1.f / (1.f + __expf(-zi));
      float gf = 1.f / (1.f + __expf(-zf));
      float go = 1.f / (1.f + __expf(-zo));
      float cnew = gf * c_reg[ch] + gi * tanhf(zg);
      float hn = go * tanhf(cnew);
      c_reg[ch] = cnew;

      if (t < 30) {   // h(31) never read (t=31 GEMM skipped)
        float hs = hn * 256.f;
        float hb = __shfl_xor(hs, 1);
        float lo = (rr & 1) ? hb : hs;
        float hi = (rr & 1) ? hs : hb;
        unsigned pk = (unsigned)__builtin_amdgcn_cvt_pk_fp8_f32(lo, hi, 0, false) & 0xFFFFu;
        unsigned pk2 = (unsigned)__shfl_xor((int)pk, 2);
        unsigned word = pk | (pk2 << 16);
        if (!s_ && (rr & 3) == 0)
          store_agent_u32((unsigned*)(a8nxt + (size_t)rowg * AROW + v), word);
      }

      {  // stats for step t+1 (token t+1 <= 31)
        int tok = tokens[rowg * TLEN + t + 1];
        float e = __expf(hn);
        float sl = (v < tok) ? e : 0.f;
        float st_ = (v == tok) ? e : 0.f;
#pragma unroll
        for (int mm = 1; mm <= 4; mm <<= 1) {
          e += __shfl_xor(e, mm);
          sl += __shfl_xor(sl, mm);
          st_ += __shfl_xor(st_, mm);
        }
        if (rr == 0) {
          float* stn = stats + (par ^ 1) * 3 * BATCH * NCG;
          store_agent_f32(&stn[(0 * BATCH + rowg) * NCG + cg], e);
          store_agent_f32(&stn[(1 * BATCH + rowg) * NCG + cg], sl);
          store_agent_f32(&stn[(2 * BATCH + rowg) * NCG + cg], st_);
        }
      }

      // arrive (syncthreads drains all waves' stores first)
      __syncthreads();
      if (tid == 0) store_agent_u32(arrv + j, (unsigned)(t + 1));
    }
  }

  // ---- bounds for t=31, then finalize out (blocks j<64 only) ----
  if (j < BATCH) {
    chain_wait((j < 32) ? arrvA : arrvB, 31u, tid, lane);
    if (wid < 3) {
      const float* st = stats + 1 * 3 * BATCH * NCG +   // par of t=31 is 1
                        (wid * BATCH + j) * NCG + lane * 4;
      float2 a_ = load_agent_f32x2(st);
      float2 b_ = load_agent_f32x2(st + 2);
      float a = a_.x + a_.y + b_.x + b_.y;
#pragma unroll
      for (int mm = 1; mm <= 32; mm <<= 1) a += __shfl_xor(a, mm);
      if (lane == 0) spart[31][wid] = a;
    }
    __syncthreads();
    if (tid < TLEN) {
      float val;
      if (tid == 0) {
        int tk = tokens[j * TLEN];
        val = 1.5f * (2.f * tk + 1.f) * (1.f / 2048.f);
      } else {
        float S  = spart[tid][0];
        float SL = spart[tid][1];
        float ST = spart[tid][2];
        val = 1.5f * (2.f * SL + ST) / S;
      }
      sval[tid] = val;
    }
    __syncthreads();
    for (int idx = tid; idx < TLEN * 64; idx += 512) {
      int tp = idx >> 6, d = idx & 63;
      out[j * TLEN * 64 + idx] = (d < TLEN && d <= tp) ? sval[d] : 1.5f;
    }
  }
}

extern "C" void kernel_launch(void* const* d_in, const int* in_sizes, int n_in,
                              void* d_out, int out_size, void* d_ws, size_t ws_size,
                              hipStream_t stream) {
  (void)in_sizes; (void)n_in; (void)out_size; (void)ws_size;
  const int* tokens = (const int*)d_in[0];
  const float* emb  = (const float*)d_in[1];
  const float* Wx   = (const float*)d_in[2];
  const float* Wh   = (const float*)d_in[3];
  const float* bias = (const float*)d_in[4];
  float* out = (float*)d_out;
  char* ws = (char*)d_ws;

  unsigned char* B8 = (unsigned char*)(ws);                  // 18,874,368 B
  unsigned char* a8 = (unsigned char*)(ws + 18874368);       //  4,866,048 B (33 slots)
  float* stats      = (float*)(ws + 23740416);               //    393,216 B
  unsigned* arrvA   = (unsigned*)(ws + 24133632);            //      1,024 B
  unsigned* arrvB   = (unsigned*)(ws + 24134656);            //      1,024 B

  k_init<<<512, 256, 0, stream>>>(a8, arrvA);
  k_conv<<<4096, 256, 0, stream>>>(Wh, B8, 0);      // Wh: K rows 0..2048
  k_conv<<<512, 256, 0, stream>>>(Wx, B8, 2048);    // Wx: K rows 2048..2304
  k_gather<<<512, 256, 0, stream>>>(tokens, emb, a8);
  k_persist<<<NBLK, 512, 0, stream>>>(tokens, B8, a8, bias, stats, out, arrvA, arrvB);
}

// Round 15
// 254.607 us; speedup vs baseline: 1.6221x; 1.6221x over previous
//
#include <hip/hip_runtime.h>
#include <hip/hip_bf16.h>

#define VOCAB 2048
#define EMBD  256
#define LATD  64
#define TLEN  32
#define BATCH 64
#define NBLK  256
#define NCG   128   // column groups (16 vocab cols each); rows split 2-way
#define AROW  2304                 // bytes per a8 row (h[2048] || x[256], fp8)
#define ASLOT (BATCH * AROW)       // bytes per time slot

typedef __attribute__((ext_vector_type(4))) float f32x4;

// ---------------- init: a8 slot0 h-region = 0, barrier = 0 ----------------
__global__ void k_init(unsigned char* __restrict__ a8, unsigned* __restrict__ bar) {
  int i = blockIdx.x * 256 + threadIdx.x;   // grid 512*256 = 131072
  if (i < 32768) {                           // 64 rows x 2048 B of h zeros
    int row = i >> 9;
    *(unsigned*)(a8 + (size_t)row * AROW + ((i & 511) << 2)) = 0u;
  }
  if (i < 384) bar[i] = 0;                   // 256 arrv + 128 rel words
}

// -------- transpose+convert: src[K][8192] f32 -> B8[n][koff+k] fp8*32 --------
__global__ void k_conv(const float* __restrict__ src,
                       unsigned char* __restrict__ dst, int koff) {
  __shared__ unsigned char tile[64][80];     // [n][k], 80 -> 16B-aligned rows
  int k0 = (blockIdx.x >> 7) * 64;
  int n0 = (blockIdx.x & 127) * 64;
  int tid = threadIdx.x;
  {
    int kl = tid >> 2;
    int nq = (tid & 3) << 4;
    const float* s = src + (size_t)(k0 + kl) * 8192 + n0 + nq;
#pragma unroll
    for (int i = 0; i < 4; ++i) {
      float4 v = *reinterpret_cast<const float4*>(s + i * 4);
      unsigned pa = (unsigned)__builtin_amdgcn_cvt_pk_fp8_f32(v.x * 32.f, v.y * 32.f, 0, false);
      unsigned pb = (unsigned)__builtin_amdgcn_cvt_pk_fp8_f32(v.z * 32.f, v.w * 32.f, 0, false);
      tile[nq + i * 4 + 0][kl] = (unsigned char)(pa & 0xFF);
      tile[nq + i * 4 + 1][kl] = (unsigned char)((pa >> 8) & 0xFF);
      tile[nq + i * 4 + 2][kl] = (unsigned char)(pb & 0xFF);
      tile[nq + i * 4 + 3][kl] = (unsigned char)((pb >> 8) & 0xFF);
    }
  }
  __syncthreads();
  {
    int nl = tid >> 2;
    int kq = (tid & 3) << 4;
    *(uint4*)(dst + (size_t)(n0 + nl) * AROW + koff + k0 + kq) =
        *(const uint4*)&tile[nl][kq];
  }
}

// ---- gather: a8[t][b][2048+c] = fp8(emb[tokens[b][t]][c] * 256) ----
__global__ void k_gather(const int* __restrict__ tokens,
                         const float* __restrict__ emb,
                         unsigned char* __restrict__ a8) {
  int tid = threadIdx.x;
  int row = blockIdx.x * 4 + (tid >> 6);   // 512 blocks -> 2048 rows
  int lane = tid & 63;
  int t = row >> 6, b = row & 63;
  int tok = tokens[b * TLEN + t];
  float4 v = *reinterpret_cast<const float4*>(emb + (size_t)tok * EMBD + lane * 4);
  unsigned pa = (unsigned)__builtin_amdgcn_cvt_pk_fp8_f32(v.x * 256.f, v.y * 256.f, 0, false);
  unsigned pb = (unsigned)__builtin_amdgcn_cvt_pk_fp8_f32(v.z * 256.f, v.w * 256.f, 0, false);
  *(unsigned*)(a8 + (size_t)t * ASLOT + (size_t)b * AROW + 2048 + lane * 4) =
      (pa & 0xFFFFu) | (pb << 16);
}

__device__ __forceinline__ void store_agent_u32(unsigned* p, unsigned v) {
  __hip_atomic_store(p, v, __ATOMIC_RELAXED, __HIP_MEMORY_SCOPE_AGENT);
}
__device__ __forceinline__ unsigned load_agent_u32(const unsigned* p) {
  return __hip_atomic_load(p, __ATOMIC_RELAXED, __HIP_MEMORY_SCOPE_AGENT);
}
__device__ __forceinline__ unsigned long long load_agent_u64(const void* p) {
  return __hip_atomic_load((const unsigned long long*)p, __ATOMIC_RELAXED,
                           __HIP_MEMORY_SCOPE_AGENT);
}
__device__ __forceinline__ void store_agent_f32(float* p, float v) {
  __hip_atomic_store(p, v, __ATOMIC_RELAXED, __HIP_MEMORY_SCOPE_AGENT);
}

// Two-hop store-based grid barrier (round-7/10/13 design, best measured).
__device__ __forceinline__ void grid_barrier(unsigned* arrv, unsigned* rel,
                                             int t, int j, int tid, int lane) {
  __syncthreads();
  const unsigned want = (unsigned)(t + 1);
  if (j == 0) {
    if (tid < 64) {                      // wave 0
      if (lane == 0) store_agent_u32(arrv, want);
      for (;;) {
        unsigned long long a = load_agent_u64(arrv + 2 * lane);
        unsigned long long b = load_agent_u64(arrv + 128 + 2 * lane);
        bool ok = ((unsigned)a >= want) && ((unsigned)(a >> 32) >= want) &&
                  ((unsigned)b >= want) && ((unsigned)(b >> 32) >= want);
        if (__all(ok)) break;
      }
      if (lane < 8) store_agent_u32(rel + (lane << 4), want);
    }
  } else {
    if (tid == 0) {
      store_agent_u32(arrv + j, want);
      while (load_agent_u32(rel + ((j & 7) << 4)) < want)
        __builtin_amdgcn_s_sleep(1);
    }
  }
  __syncthreads();
}

// ---------------- persistent kernel: steps 0..30 (t=31 GEMM is dead) ----------------
// r13 structure (fp8 GEMM, B panel in 72 VGPRs, two-hop barrier) with a
// block-UNIFORM t-loop: stats go to a 31-slot ring (store-only in-loop);
// all bounds reads happen once after the loop -> no designated-slow blocks
// stretching every barrier. h-store skipped at t=30 (a8[31] never read).
__global__ __launch_bounds__(512, 1) void k_persist(
    const int* __restrict__ tokens,
    const unsigned char* __restrict__ B8,     // [8192][2304] fp8 (W*32)
    unsigned char* __restrict__ a8,           // [33][64][2304] fp8 (h||x)*256
    const float* __restrict__ bias,           // [8192]
    float* __restrict__ stats,                // [31][3][64][128] ring
    float* __restrict__ out,                  // [64][32][64]
    unsigned* __restrict__ arrv,              // [256]
    unsigned* __restrict__ rel) {             // [8*16]
  const int tid = threadIdx.x;
  const int lane = tid & 63;
  const int wid = tid >> 6;                  // 0..7 = K-split (288 B each)
  const int j = blockIdx.x;                  // physical id (barrier, bounds)
  const int cg = (j & 7) | ((j >> 4) << 3);  // column group 0..127 (swizzled)
  const int rg = (j >> 3) & 1;               // row group 0..1
  const int r0 = rg << 5;                    // first batch row

  __shared__ float racc[8][2][4][4][64];   // [wid][mf][gt][r][lane] 64KB
  __shared__ float sval[TLEN];

  const int rr = lane & 15;
  const int kg = lane >> 4;                 // 0..3 (K-subgroups of 8 bytes)

  // ---- B panel resident in VGPRs (72 regs), loaded once ----
  long Bf[9][4];
  {
    const unsigned char* b8B[4];
#pragma unroll
    for (int gt = 0; gt < 4; ++gt)
      b8B[gt] = B8 + (size_t)((gt << 11) + (cg << 4) + rr) * AROW + wid * 288 + kg * 8;
#pragma unroll
    for (int it = 0; it < 9; ++it)
#pragma unroll
      for (int gt = 0; gt < 4; ++gt)
        Bf[it][gt] = *(const long*)(b8B[gt] + it * 32);
  }

  // ---- epilogue constants: this thread owns cell (rowg, v) ----
  const int m_e = wid >> 2;                 // 0..1
  const int r_e = wid & 3;                  // 0..3
  const int rowg = r0 + m_e * 16 + kg * 4 + r_e;   // global batch row
  const int v = (cg << 4) + rr;             // global vocab col
  float bias_r[4];
#pragma unroll
  for (int gt = 0; gt < 4; ++gt) bias_r[gt] = bias[gt * 2048 + v];
  float c_reg = 0.f;

  for (int t = 0; t <= 30; ++t) {            // t=31's GEMM output is never read
    const unsigned char* a8cur = a8 + (size_t)t * ASLOT;
    unsigned char* a8next = a8 + (size_t)(t + 1) * ASLOT;
    const int tok = tokens[rowg * TLEN + t + 1];

    // ---- GEMM: z[32 rows x 64 zcols] over K=2304 fp8, 8 waves split K ----
    f32x4 acc[2][4];
#pragma unroll
    for (int mf = 0; mf < 2; ++mf)
#pragma unroll
      for (int gt = 0; gt < 4; ++gt) acc[mf][gt] = (f32x4){0.f, 0.f, 0.f, 0.f};

    const unsigned char* aB = a8cur + (size_t)(r0 + rr) * AROW + wid * 288 + kg * 8;
    long Ar[4][2];
    auto issue = [&](int it) {
      int slot = it & 3;
      Ar[slot][0] = *(const long*)(aB + it * 32);
      Ar[slot][1] = *(const long*)(aB + 16 * AROW + it * 32);
    };

#pragma unroll
    for (int it = 0; it < 4; ++it) issue(it);
#pragma unroll
    for (int it = 0; it < 9; ++it) {
      const int sl = it & 3;
#pragma unroll
      for (int gt = 0; gt < 4; ++gt) {
        acc[0][gt] = __builtin_amdgcn_mfma_f32_16x16x32_fp8_fp8(Ar[sl][0], Bf[it][gt], acc[0][gt], 0, 0, 0);
        acc[1][gt] = __builtin_amdgcn_mfma_f32_16x16x32_fp8_fp8(Ar[sl][1], Bf[it][gt], acc[1][gt], 0, 0, 0);
      }
      if (it + 4 < 9) issue(it + 4);
    }

    // ---- cross-wave K reduction ----
#pragma unroll
    for (int mf = 0; mf < 2; ++mf)
#pragma unroll
      for (int gt = 0; gt < 4; ++gt)
#pragma unroll
        for (int r = 0; r < 4; ++r) racc[wid][mf][gt][r][lane] = acc[mf][gt][r];
    __syncthreads();

    // ---- epilogue: one cell per thread; all 4 gates from LDS ----
    float z[4];
#pragma unroll
    for (int gt = 0; gt < 4; ++gt) {
      float s = 0.f;
#pragma unroll
      for (int w = 0; w < 8; ++w) s += racc[w][m_e][gt][r_e][lane];
      z[gt] = s * (1.f / 8192.f) + bias_r[gt];
    }
    float gi = 1.f / (1.f + __expf(-z[0]));
    float gf = 1.f / (1.f + __expf(-z[1]));
    float go = 1.f / (1.f + __expf(-z[3]));
    float cnew = gf * c_reg + gi * tanhf(z[2]);
    float hn = go * tanhf(cnew);
    c_reg = cnew;

    // h store: fp8(hn*256), pack 4 cols -> one u32 agent store per 4 lanes
    if (t < 30) {                            // a8[31] is never read
      float hs = hn * 256.f;
      float hb = __shfl_xor(hs, 1);
      float lo = (rr & 1) ? hb : hs;
      float hi = (rr & 1) ? hs : hb;
      unsigned pk = (unsigned)__builtin_amdgcn_cvt_pk_fp8_f32(lo, hi, 0, false) & 0xFFFFu;
      unsigned pk2 = (unsigned)__shfl_xor((int)pk, 2);
      unsigned word = pk | (pk2 << 16);       // valid on lanes with (rr&3)==0
      if ((rr & 3) == 0)
        store_agent_u32((unsigned*)(a8next + (size_t)rowg * AROW + v), word);
    }

    // stats partials -> ring slot t (consumed only after the loop)
    float e = __expf(hn);
    float sl = (v < tok) ? e : 0.f;
    float st = (v == tok) ? e : 0.f;
#pragma unroll
    for (int mm = 1; mm <= 8; mm <<= 1) {
      e += __shfl_xor(e, mm);
      sl += __shfl_xor(sl, mm);
      st += __shfl_xor(st, mm);
    }
    if (rr == 0) {
      float* stn = stats + (size_t)t * 3 * BATCH * NCG;
      store_agent_f32(&stn[(0 * BATCH + rowg) * NCG + cg], e);
      store_agent_f32(&stn[(1 * BATCH + rowg) * NCG + cg], sl);
      store_agent_f32(&stn[(2 * BATCH + rowg) * NCG + cg], st);
    }

    grid_barrier(arrv, rel, t, j, tid, lane);   // also orders the final reads
  }

  // ---- post-loop: bounds for all t, then write out (blocks j<64 only) ----
  if (j < BATCH) {
    // sval[tt]: wave w handles tt = w, w+8, w+16, w+24; slot tt-1 of the ring
    for (int tt = wid; tt < TLEN; tt += 8) {
      float val;
      if (tt == 0) {
        int tk = tokens[j * TLEN];
        val = 1.5f * (2.f * tk + 1.f) * (1.f / 2048.f);
      } else {
        const float* st = stats + (size_t)(tt - 1) * 3 * BATCH * NCG;
        float2 u0 = *reinterpret_cast<const float2*>(st + (0 * BATCH + j) * NCG + lane * 2);
        float2 u1 = *reinterpret_cast<const float2*>(st + (1 * BATCH + j) * NCG + lane * 2);
        float2 u2 = *reinterpret_cast<const float2*>(st + (2 * BATCH + j) * NCG + lane * 2);
        float a0 = u0.x + u0.y, a1 = u1.x + u1.y, a2 = u2.x + u2.y;
#pragma unroll
        for (int mm = 1; mm <= 32; mm <<= 1) {
          a0 += __shfl_xor(a0, mm);
          a1 += __shfl_xor(a1, mm);
          a2 += __shfl_xor(a2, mm);
        }
        val = 1.5f * (2.f * a1 + a2) / a0;
      }
      if (lane == 0) sval[tt] = val;
    }
    __syncthreads();
    for (int idx = tid; idx < TLEN * LATD; idx += 512) {
      int tp = idx >> 6, d = idx & 63;
      out[j * TLEN * LATD + idx] = (d < TLEN && d <= tp) ? sval[d] : 1.5f;
    }
  }
}

extern "C" void kernel_launch(void* const* d_in, const int* in_sizes, int n_in,
                              void* d_out, int out_size, void* d_ws, size_t ws_size,
                              hipStream_t stream) {
  (void)in_sizes; (void)n_in; (void)out_size; (void)ws_size;
  const int* tokens = (const int*)d_in[0];
  const float* emb  = (const float*)d_in[1];
  const float* Wx   = (const float*)d_in[2];
  const float* Wh   = (const float*)d_in[3];
  const float* bias = (const float*)d_in[4];
  float* out = (float*)d_out;
  char* ws = (char*)d_ws;

  unsigned char* B8 = (unsigned char*)(ws);                  // 18,874,368 B
  unsigned char* a8 = (unsigned char*)(ws + 18874368);       //  4,866,048 B (33 slots)
  float* stats      = (float*)(ws + 23740416);               //  3,047,424 B (31 slots)
  unsigned* arrv    = (unsigned*)(ws + 26787840);            //      1,024 B
  unsigned* rel     = (unsigned*)(ws + 26788864);            //        512 B

  k_init<<<512, 256, 0, stream>>>(a8, arrv);
  k_conv<<<4096, 256, 0, stream>>>(Wh, B8, 0);      // Wh: K rows 0..2048
  k_conv<<<512, 256, 0, stream>>>(Wx, B8, 2048);    // Wx: K rows 2048..2304
  k_gather<<<512, 256, 0, stream>>>(tokens, emb, a8);
  k_persist<<<NBLK, 512, 0, stream>>>(tokens, B8, a8, bias, stats, out, arrv, rel);
}

// Round 16
// 247.280 us; speedup vs baseline: 1.6701x; 1.0296x over previous
//
#include <hip/hip_runtime.h>
#include <hip/hip_bf16.h>

#define VOCAB 2048
#define EMBD  256
#define LATD  64
#define TLEN  32
#define BATCH 64
#define NBLK  256
#define NCG   128   // column groups (16 vocab cols each); rows split 2-way
#define AROW  2304                 // bytes per a8 row (h[2048] || x[256], fp8)
#define ASLOT (BATCH * AROW)       // bytes per time slot
#define BARW  512                  // hArr[256] + hRel[16 lines x 16]

typedef __attribute__((ext_vector_type(4))) float f32x4;

// ---------------- init: a8 slot0 h-region = 0, barrier = 0 ----------------
__global__ void k_init(unsigned char* __restrict__ a8, unsigned* __restrict__ bar) {
  int i = blockIdx.x * 256 + threadIdx.x;   // grid 512*256 = 131072
  if (i < 32768) {                           // 64 rows x 2048 B of h zeros
    int row = i >> 9;
    *(unsigned*)(a8 + (size_t)row * AROW + ((i & 511) << 2)) = 0u;
  }
  if (i < BARW) bar[i] = 0;
}

// -------- transpose+convert: src[K][8192] f32 -> B8[n][koff+k] fp8*32 --------
__global__ void k_conv(const float* __restrict__ src,
                       unsigned char* __restrict__ dst, int koff) {
  __shared__ unsigned char tile[64][80];     // [n][k], 80 -> 16B-aligned rows
  int k0 = (blockIdx.x >> 7) * 64;
  int n0 = (blockIdx.x & 127) * 64;
  int tid = threadIdx.x;
  {
    int kl = tid >> 2;
    int nq = (tid & 3) << 4;
    const float* s = src + (size_t)(k0 + kl) * 8192 + n0 + nq;
#pragma unroll
    for (int i = 0; i < 4; ++i) {
      float4 v = *reinterpret_cast<const float4*>(s + i * 4);
      unsigned pa = (unsigned)__builtin_amdgcn_cvt_pk_fp8_f32(v.x * 32.f, v.y * 32.f, 0, false);
      unsigned pb = (unsigned)__builtin_amdgcn_cvt_pk_fp8_f32(v.z * 32.f, v.w * 32.f, 0, false);
      tile[nq + i * 4 + 0][kl] = (unsigned char)(pa & 0xFF);
      tile[nq + i * 4 + 1][kl] = (unsigned char)((pa >> 8) & 0xFF);
      tile[nq + i * 4 + 2][kl] = (unsigned char)(pb & 0xFF);
      tile[nq + i * 4 + 3][kl] = (unsigned char)((pb >> 8) & 0xFF);
    }
  }
  __syncthreads();
  {
    int nl = tid >> 2;
    int kq = (tid & 3) << 4;
    *(uint4*)(dst + (size_t)(n0 + nl) * AROW + koff + k0 + kq) =
        *(const uint4*)&tile[nl][kq];
  }
}

// ---- gather: a8[t][b][2048+c] = fp8(emb[tokens[b][t]][c] * 256) ----
__global__ void k_gather(const int* __restrict__ tokens,
                         const float* __restrict__ emb,
                         unsigned char* __restrict__ a8) {
  int tid = threadIdx.x;
  int row = blockIdx.x * 4 + (tid >> 6);   // 512 blocks -> 2048 rows
  int lane = tid & 63;
  int t = row >> 6, b = row & 63;
  int tok = tokens[b * TLEN + t];
  float4 v = *reinterpret_cast<const float4*>(emb + (size_t)tok * EMBD + lane * 4);
  unsigned pa = (unsigned)__builtin_amdgcn_cvt_pk_fp8_f32(v.x * 256.f, v.y * 256.f, 0, false);
  unsigned pb = (unsigned)__builtin_amdgcn_cvt_pk_fp8_f32(v.z * 256.f, v.w * 256.f, 0, false);
  *(unsigned*)(a8 + (size_t)t * ASLOT + (size_t)b * AROW + 2048 + lane * 4) =
      (pa & 0xFFFFu) | (pb << 16);
}

__device__ __forceinline__ void store_agent_u32(unsigned* p, unsigned v) {
  __hip_atomic_store(p, v, __ATOMIC_RELAXED, __HIP_MEMORY_SCOPE_AGENT);
}
__device__ __forceinline__ unsigned load_agent_u32(const unsigned* p) {
  return __hip_atomic_load(p, __ATOMIC_RELAXED, __HIP_MEMORY_SCOPE_AGENT);
}
__device__ __forceinline__ unsigned long long load_agent_u64(const void* p) {
  return __hip_atomic_load((const unsigned long long*)p, __ATOMIC_RELAXED,
                           __HIP_MEMORY_SCOPE_AGENT);
}
__device__ __forceinline__ void store_agent_f32(float* p, float v) {
  __hip_atomic_store(p, v, __ATOMIC_RELAXED, __HIP_MEMORY_SCOPE_AGENT);
}
__device__ __forceinline__ float2 load_agent_f32x2(const float* p) {
  unsigned long long u = load_agent_u64(p);
  float2 f;
  __builtin_memcpy(&f, &u, 8);
  return f;
}

// rg-local half barrier: syncs only the 128 blocks of one row-group.
// A-reads are rg-local; bounds duty is remapped so every in-loop stats read
// is also rg-local. Store-based, monotone, two hops per rg.
__device__ __forceinline__ void half_barrier(unsigned* bar, int t, int cg,
                                             int rg, int xg, int tid, int lane) {
  __syncthreads();                        // all waves' agent stores drained
  const unsigned want = (unsigned)(t + 1);
  unsigned* hArr = bar + rg * 128;
  unsigned* hRel = bar + 256;
  if (cg == 0) {
    if (tid < 64) {                       // leader wave polls its 128 words
      if (lane == 0) store_agent_u32(hArr, want);
      for (;;) {
        unsigned long long a = load_agent_u64(hArr + 2 * lane);
        bool ok = ((unsigned)a >= want) && ((unsigned)(a >> 32) >= want);
        if (__all(ok)) break;
      }
      if (lane < 8) store_agent_u32(hRel + ((rg * 8 + lane) << 4), want);
    }
  } else {
    if (tid == 0) {
      store_agent_u32(hArr + cg, want);
      while (load_agent_u32(hRel + ((rg * 8 + xg) << 4)) < want)
        __builtin_amdgcn_s_sleep(1);
    }
  }
  __syncthreads();
}

// ---------------- persistent kernel: steps 0..30 (t=31 GEMM is dead) ----------------
// r13 structure (fp8 GEMM, B panel in 72 VGPRs, 2-slot stats ping-pong,
// in-loop deferred bounds) with: (1) dead t=31 step cut, (2) rg-local half
// barriers, (3) bounds duty remapped to same-rg blocks: block (rg, cg<32)
// handles batch row rg*32+cg (stats reads then rg-local => half-barrier safe).
__global__ __launch_bounds__(512, 1) void k_persist(
    const int* __restrict__ tokens,
    const unsigned char* __restrict__ B8,     // [8192][2304] fp8 (W*32)
    unsigned char* __restrict__ a8,           // [33][64][2304] fp8 (h||x)*256
    const float* __restrict__ bias,           // [8192]
    float* __restrict__ stats,                // [2][3][64][128]
    float* __restrict__ out,                  // [64][32][64]
    unsigned* __restrict__ bar) {             // [BARW]
  const int tid = threadIdx.x;
  const int lane = tid & 63;
  const int wid = tid >> 6;                  // 0..7 = K-split (288 B each)
  const int j = blockIdx.x;                  // physical id
  const int cg = (j & 7) | ((j >> 4) << 3);  // column group 0..127 (swizzled)
  const int rg = (j >> 3) & 1;               // row group 0..1
  const int xg = j & 7;                      // XCD-ish group for rel lines
  const int r0 = rg << 5;                    // first batch row
  const int b_own = r0 + cg;                 // bounds row (valid when cg<32)

  __shared__ float racc[8][2][4][4][64];   // [wid][mf][gt][r][lane] 64KB
  __shared__ float spart[TLEN][3];         // deferred bounds partials
  __shared__ float sval[TLEN];

  const int rr = lane & 15;
  const int kg = lane >> 4;                 // 0..3 (K-subgroups of 8 bytes)

  // ---- B panel resident in VGPRs (72 regs), loaded once ----
  long Bf[9][4];
  {
    const unsigned char* b8B[4];
#pragma unroll
    for (int gt = 0; gt < 4; ++gt)
      b8B[gt] = B8 + (size_t)((gt << 11) + (cg << 4) + rr) * AROW + wid * 288 + kg * 8;
#pragma unroll
    for (int it = 0; it < 9; ++it)
#pragma unroll
      for (int gt = 0; gt < 4; ++gt)
        Bf[it][gt] = *(const long*)(b8B[gt] + it * 32);
  }

  // ---- epilogue constants: this thread owns cell (rowg, v) ----
  const int m_e = wid >> 2;                 // 0..1
  const int r_e = wid & 3;                  // 0..3
  const int rowg = r0 + m_e * 16 + kg * 4 + r_e;   // global batch row
  const int v = (cg << 4) + rr;             // global vocab col
  float bias_r[4];
#pragma unroll
  for (int gt = 0; gt < 4; ++gt) bias_r[gt] = bias[gt * 2048 + v];
  float c_reg = 0.f;

  for (int t = 0; t <= 30; ++t) {            // t=31's GEMM output is never read
    const int par = t & 1;
    const unsigned char* a8cur = a8 + (size_t)t * ASLOT;
    unsigned char* a8next = a8 + (size_t)(t + 1) * ASLOT;
    const int tok = tokens[rowg * TLEN + t + 1];

    // ---- distributed bounds load: waves 0..2 of blocks with cg<32 ----
    float2 sv;
    const bool do_stat = (t > 0) && (cg < 32) && (wid < 3);
    if (do_stat)
      sv = load_agent_f32x2(stats + par * 3 * BATCH * NCG +
                            (wid * BATCH + b_own) * NCG + lane * 2);

    // ---- GEMM: z[32 rows x 64 zcols] over K=2304 fp8, 8 waves split K ----
    f32x4 acc[2][4];
#pragma unroll
    for (int mf = 0; mf < 2; ++mf)
#pragma unroll
      for (int gt = 0; gt < 4; ++gt) acc[mf][gt] = (f32x4){0.f, 0.f, 0.f, 0.f};

    const unsigned char* aB = a8cur + (size_t)(r0 + rr) * AROW + wid * 288 + kg * 8;
    long Ar[4][2];
    auto issue = [&](int it) {
      int slot = it & 3;
      Ar[slot][0] = *(const long*)(aB + it * 32);
      Ar[slot][1] = *(const long*)(aB + 16 * AROW + it * 32);
    };

#pragma unroll
    for (int it = 0; it < 4; ++it) issue(it);
#pragma unroll
    for (int it = 0; it < 9; ++it) {
      const int sl = it & 3;
#pragma unroll
      for (int gt = 0; gt < 4; ++gt) {
        acc[0][gt] = __builtin_amdgcn_mfma_f32_16x16x32_fp8_fp8(Ar[sl][0], Bf[it][gt], acc[0][gt], 0, 0, 0);
        acc[1][gt] = __builtin_amdgcn_mfma_f32_16x16x32_fp8_fp8(Ar[sl][1], Bf[it][gt], acc[1][gt], 0, 0, 0);
      }
      if (it + 4 < 9) issue(it + 4);
    }

    // ---- cross-wave K reduction ----
#pragma unroll
    for (int mf = 0; mf < 2; ++mf)
#pragma unroll
      for (int gt = 0; gt < 4; ++gt)
#pragma unroll
        for (int r = 0; r < 4; ++r) racc[wid][mf][gt][r][lane] = acc[mf][gt][r];
    __syncthreads();

    // ---- deferred bounds partial: reduce sv across wave, park in LDS ----
    if (do_stat) {
      float a = sv.x + sv.y;
#pragma unroll
      for (int mm = 1; mm <= 32; mm <<= 1) a += __shfl_xor(a, mm);
      if (lane == 0) spart[t][wid] = a;
    }

    // ---- epilogue: one cell per thread; all 4 gates from LDS ----
    float z[4];
#pragma unroll
    for (int gt = 0; gt < 4; ++gt) {
      float s = 0.f;
#pragma unroll
      for (int w = 0; w < 8; ++w) s += racc[w][m_e][gt][r_e][lane];
      z[gt] = s * (1.f / 8192.f) + bias_r[gt];
    }
    float gi = 1.f / (1.f + __expf(-z[0]));
    float gf = 1.f / (1.f + __expf(-z[1]));
    float go = 1.f / (1.f + __expf(-z[3]));
    float cnew = gf * c_reg + gi * tanhf(z[2]);
    float hn = go * tanhf(cnew);
    c_reg = cnew;

    // h store: fp8(hn*256), pack 4 cols -> one u32 agent store per 4 lanes
    if (t < 30) {                            // a8[31] is never read
      float hs = hn * 256.f;
      float hb = __shfl_xor(hs, 1);
      float lo = (rr & 1) ? hb : hs;
      float hi = (rr & 1) ? hs : hb;
      unsigned pk = (unsigned)__builtin_amdgcn_cvt_pk_fp8_f32(lo, hi, 0, false) & 0xFFFFu;
      unsigned pk2 = (unsigned)__shfl_xor((int)pk, 2);
      unsigned word = pk | (pk2 << 16);       // valid on lanes with (rr&3)==0
      if ((rr & 3) == 0)
        store_agent_u32((unsigned*)(a8next + (size_t)rowg * AROW + v), word);
    }

    // stats partials over this block's 16 cols (2-slot ping-pong, LLC-warm)
    float e = __expf(hn);
    float sl = (v < tok) ? e : 0.f;
    float st = (v == tok) ? e : 0.f;
#pragma unroll
    for (int mm = 1; mm <= 8; mm <<= 1) {
      e += __shfl_xor(e, mm);
      sl += __shfl_xor(sl, mm);
      st += __shfl_xor(st, mm);
    }
    if (rr == 0) {
      float* stn = stats + (par ^ 1) * 3 * BATCH * NCG;
      store_agent_f32(&stn[(0 * BATCH + rowg) * NCG + cg], e);
      store_agent_f32(&stn[(1 * BATCH + rowg) * NCG + cg], sl);
      store_agent_f32(&stn[(2 * BATCH + rowg) * NCG + cg], st);
    }

    half_barrier(bar, t, cg, rg, xg, tid, lane);  // t=30's also orders finals
  }

  // ---- post-loop: spart[31] from slot 1, then sval + out (cg<32 blocks) ----
  if (cg < 32) {
    if (wid < 3) {
      float2 sv = load_agent_f32x2(stats + 1 * 3 * BATCH * NCG +   // par(t=31)=1
                                   (wid * BATCH + b_own) * NCG + lane * 2);
      float a = sv.x + sv.y;
#pragma unroll
      for (int mm = 1; mm <= 32; mm <<= 1) a += __shfl_xor(a, mm);
      if (lane == 0) spart[31][wid] = a;
    }
    __syncthreads();
    if (tid < TLEN) {
      float val;
      if (tid == 0) {
        int tk = tokens[b_own * TLEN];
        val = 1.5f * (2.f * tk + 1.f) * (1.f / 2048.f);
      } else {
        float S  = spart[tid][0];
        float SL = spart[tid][1];
        float ST = spart[tid][2];
        val = 1.5f * (2.f * SL + ST) / S;
      }
      sval[tid] = val;
    }
    __syncthreads();
    for (int idx = tid; idx < TLEN * LATD; idx += 512) {
      int tp = idx >> 6, d = idx & 63;
      out[b_own * TLEN * LATD + idx] = (d < TLEN && d <= tp) ? sval[d] : 1.5f;
    }
  }
}

extern "C" void kernel_launch(void* const* d_in, const int* in_sizes, int n_in,
                              void* d_out, int out_size, void* d_ws, size_t ws_size,
                              hipStream_t stream) {
  (void)in_sizes; (void)n_in; (void)out_size; (void)ws_size;
  const int* tokens = (const int*)d_in[0];
  const float* emb  = (const float*)d_in[1];
  const float* Wx   = (const float*)d_in[2];
  const float* Wh   = (const float*)d_in[3];
  const float* bias = (const float*)d_in[4];
  float* out = (float*)d_out;
  char* ws = (char*)d_ws;

  unsigned char* B8 = (unsigned char*)(ws);                  // 18,874,368 B
  unsigned char* a8 = (unsigned char*)(ws + 18874368);       //  4,866,048 B (33 slots)
  float* stats      = (float*)(ws + 23740416);               //    196,608 B
  unsigned* bar     = (unsigned*)(ws + 23937024);            //      2,048 B

  k_init<<<512, 256, 0, stream>>>(a8, bar);
  k_conv<<<4096, 256, 0, stream>>>(Wh, B8, 0);      // Wh: K rows 0..2048
  k_conv<<<512, 256, 0, stream>>>(Wx, B8, 2048);    // Wx: K rows 2048..2304
  k_gather<<<512, 256, 0, stream>>>(tokens, emb, a8);
  k_persist<<<NBLK, 512, 0, stream>>>(tokens, B8, a8, bias, stats, out, bar);
}